// Round 9
// baseline (19.607 us; speedup 1.0000x reference)
//
#include <hip/hip_runtime.h>

#define N_PAT 4096
#define NMOD  4
#define OFFPAIRS 16773120.0   // N*(N-1)

// ---------------------------------------------------------------------------
// K1: blocks 0..1023 = prep. Block b covers 16 rows (one modality, m = b>>8;
//     wave w handles rows b*16 + w*4 .. +3, register-accumulated):
//       xn = x/max(||x||,eps); valid = !missing; acc += valid*xn
//       D += valid*ss/denom^2 ; n += valid
//     -> part_v[b][256], part_D[b], part_n[b].   Block 0 zeroes ctr.
// blocks 1024..1279 = cox: for its 16 i's computes sumexp AND the cox
//     num/den contribution inline -> num_part[cb], den_part[cb].
// ---------------------------------------------------------------------------
__global__ __launch_bounds__(256) void prep_cox_kernel(
    const float* __restrict__ eb, const float* __restrict__ h,
    const float* __restrict__ t, const int* __restrict__ ev,
    float* __restrict__ part_v, float* __restrict__ part_D,
    float* __restrict__ part_n, float* __restrict__ num_part,
    float* __restrict__ den_part, int* __restrict__ ctr)
{
  __shared__ float shmem[8192];             // 32 KB, shared by both paths
  __shared__ float rsh[8];
  int tid = threadIdx.x;
  int wid = tid >> 6, lane = tid & 63;
  int b = blockIdx.x;

  if (b < 1024) {
    if (b == 0 && tid == 0) *ctr = 0;
    float* xsh = shmem;                     // [4][256] per-wave masked-xn sums
    float* dsh = shmem + 1024;              // [4] D partial
    float* nsh = shmem + 1028;              // [4] n partial
    float4 acc = {0.f, 0.f, 0.f, 0.f};
    float Dacc = 0.f, nacc = 0.f;
#pragma unroll
    for (int rr = 0; rr < 4; ++rr) {
      int row = b * 16 + wid * 4 + rr;
      const float* base = eb + (size_t)row * 256;
      float4 v = *(const float4*)(base + lane * 4);
      float x0 = base[0];
      int eq = (v.x == x0) & (v.y == x0) & (v.z == x0) & (v.w == x0);
      float ss = v.x * v.x + v.y * v.y + v.z * v.z + v.w * v.w;
#pragma unroll
      for (int o = 32; o; o >>= 1) ss += __shfl_xor(ss, o, 64);
      int missing = __all(eq);
      float denom = fmaxf(sqrtf(ss), 1e-8f);
      float inv = missing ? 0.0f : (1.0f / denom);
      acc.x += v.x * inv; acc.y += v.y * inv;
      acc.z += v.z * inv; acc.w += v.w * inv;
      Dacc += missing ? 0.0f : (ss * inv * inv);   // self-cos = ss/denom^2
      nacc += missing ? 0.0f : 1.0f;
    }
    xsh[wid * 256 + lane * 4 + 0] = acc.x;
    xsh[wid * 256 + lane * 4 + 1] = acc.y;
    xsh[wid * 256 + lane * 4 + 2] = acc.z;
    xsh[wid * 256 + lane * 4 + 3] = acc.w;
    if (lane == 0) { dsh[wid] = Dacc; nsh[wid] = nacc; }
    __syncthreads();
    part_v[(size_t)b * 256 + tid] =
        (xsh[tid] + xsh[256 + tid]) + (xsh[512 + tid] + xsh[768 + tid]);
    if (tid == 0) part_D[b] = (dsh[0] + dsh[1]) + (dsh[2] + dsh[3]);
    if (tid == 1) part_n[b] = (nsh[0] + nsh[1]) + (nsh[2] + nsh[3]);
  } else {
    // ---- cox path: sumexp + num/den inline ----
    float* tl = shmem;
    float* el = shmem + 4096;
    for (int q = tid; q < N_PAT; q += 256) {
      tl[q] = t[q];
      el[q] = expf(h[q]);
    }
    __syncthreads();
    int cb = b - 1024;
    float numw = 0.f, denw = 0.f;           // lane-0 accumulators
#pragma unroll
    for (int r = 0; r < 4; ++r) {
      int i = cb * 16 + wid * 4 + r;
      float ti = tl[i];
      float s = 0.f;
#pragma unroll
      for (int it = 0; it < 16; ++it) {
        int j = (it * 64 + lane) * 4;
        float4 tv = *(const float4*)(&tl[j]);
        float4 evv = *(const float4*)(&el[j]);
        s += (tv.x >= ti) ? evv.x : 0.f;
        s += (tv.y >= ti) ? evv.y : 0.f;
        s += (tv.z >= ti) ? evv.z : 0.f;
        s += (tv.w >= ti) ? evv.w : 0.f;
      }
#pragma unroll
      for (int o = 32; o; o >>= 1) s += __shfl_xor(s, o, 64);
      if (lane == 0) {
        float e = (float)ev[i];
        numw += e * (h[i] - logf(s));
        denw += e;
      }
    }
    if (lane == 0) { rsh[wid] = numw; rsh[4 + wid] = denw; }
    __syncthreads();
    if (tid == 0) num_part[cb] = (rsh[0] + rsh[1]) + (rsh[2] + rsh[3]);
    if (tid == 1) den_part[cb] = (rsh[4] + rsh[5]) + (rsh[6] + rsh[7]);
  }
}

// ---------------------------------------------------------------------------
// K2: 16 blocks. Block g (m = g>>2, dq = g&3):
//   (1) v[m][d] for d in [dq*64, dq*64+64): sum 256 part_v rows ->
//       vsq_part[g] = sum_d v^2  (fixed-order).
//   (2) D_part16[g], n_part16[g]: sum part_D/part_n[g*64 .. +63].
//   (3) num16[g], den16[g]: sum num_part/den_part[g*16 .. +15].
// Last block (agent-scope counter) computes the final output from the 80
// partials in a FIXED order -> deterministic.
// ---------------------------------------------------------------------------
__global__ __launch_bounds__(256) void reduce_finalize_kernel(
    const float* __restrict__ part_v, const float* __restrict__ part_D,
    const float* __restrict__ part_n, const float* __restrict__ num_part,
    const float* __restrict__ den_part, const float* __restrict__ Mp,
    float* __restrict__ vsq_part, float* __restrict__ D_part16,
    float* __restrict__ n_part16, float* __restrict__ num16,
    float* __restrict__ den16, int* __restrict__ ctr,
    float* __restrict__ out)
{
  __shared__ float vsh[4][64];
  __shared__ int lastflag;
  int tid = threadIdx.x, lane = tid & 63, wid = tid >> 6;
  int g = blockIdx.x;
  int m = g >> 2, dq = g & 3;

  // (1) column sums of part_v slice (each wave 64 rows, lane = column)
  int d = dq * 64 + lane;
  const float* vb = part_v + ((size_t)(m * 256 + wid * 64)) * 256 + d;
  float s = 0.f;
#pragma unroll 8
  for (int r = 0; r < 64; ++r) s += vb[(size_t)r * 256];
  vsh[wid][lane] = s;
  __syncthreads();

  if (wid == 0) {
    float vd = (vsh[0][lane] + vsh[1][lane]) + (vsh[2][lane] + vsh[3][lane]);
    float vsq = vd * vd;
    float Dv = part_D[g * 64 + lane];
    float nv = part_n[g * 64 + lane];
    float nm = (lane < 16) ? num_part[g * 16 + lane] : 0.f;
    float dn = (lane < 16) ? den_part[g * 16 + lane] : 0.f;
#pragma unroll
    for (int o = 32; o; o >>= 1) {
      vsq += __shfl_xor(vsq, o, 64);
      Dv  += __shfl_xor(Dv, o, 64);
      nv  += __shfl_xor(nv, o, 64);
      nm  += __shfl_xor(nm, o, 64);
      dn  += __shfl_xor(dn, o, 64);
    }
    if (lane == 0) {
      vsq_part[g] = vsq;
      D_part16[g] = Dv;
      n_part16[g] = nv;
      num16[g]    = nm;
      den16[g]    = dn;
    }
  }
  __syncthreads();
  if (tid == 0) {
    __threadfence();                        // publish partials (device scope)
    int prev = __hip_atomic_fetch_add(ctr, 1, __ATOMIC_ACQ_REL,
                                      __HIP_MEMORY_SCOPE_AGENT);
    lastflag = (prev == 15);
  }
  __syncthreads();

  if (lastflag && tid == 0) {
    __threadfence();                        // acquire side
    double sim = (double)Mp[0] * OFFPAIRS;
    for (int mm = 0; mm < NMOD; ++mm) {
      double Dm = 0.0, nmm = 0.0;
      for (int q = 0; q < 4; ++q) {
        Dm  += (double)D_part16[mm * 4 + q];
        nmm += (double)n_part16[mm * 4 + q];
      }
      sim += nmm * Dm;
    }
    for (int q = 0; q < 16; ++q) sim -= (double)vsq_part[q];
    double n = 0.0, dd = 0.0;
    for (int q = 0; q < 16; ++q) { n += (double)num16[q]; dd += (double)den16[q]; }
    out[0] = (float)(-n / dd + sim);
  }
}

// ---------------------------------------------------------------------------
extern "C" void kernel_launch(void* const* d_in, const int* in_sizes, int n_in,
                              void* d_out, int out_size, void* d_ws, size_t ws_size,
                              hipStream_t stream)
{
  const float* h  = (const float*)d_in[0];
  const float* eb = (const float*)d_in[1];
  const float* tm = (const float*)d_in[2];
  const int*   ev = (const int*)d_in[3];
  const float* Mp = (const float*)d_in[4];
  float* out = (float*)d_out;

  char* ws = (char*)d_ws;
  float* part_v   = (float*)ws;                 // 1 MB  (1024 x 256)
  float* part_D   = part_v + 1024 * 256;        // 4 KB
  float* part_n   = part_D + 1024;              // 4 KB
  float* num_part = part_n + 1024;              // 1 KB
  float* den_part = num_part + 256;             // 1 KB
  float* vsq_part = den_part + 256;             // 64 B
  float* D_part16 = vsq_part + 16;              // 64 B
  float* n_part16 = D_part16 + 16;              // 64 B
  float* num16    = n_part16 + 16;              // 64 B
  float* den16    = num16 + 16;                 // 64 B
  int*   ctr      = (int*)(den16 + 16);

  prep_cox_kernel<<<dim3(1280), dim3(256), 0, stream>>>(
      eb, h, tm, ev, part_v, part_D, part_n, num_part, den_part, ctr);
  reduce_finalize_kernel<<<dim3(16), dim3(256), 0, stream>>>(
      part_v, part_D, part_n, num_part, den_part, Mp,
      vsq_part, D_part16, n_part16, num16, den16, ctr, out);
}